// Round 7
// baseline (813.100 us; speedup 1.0000x reference)
//
#include <hip/hip_runtime.h>
#include <hip/hip_bf16.h>
#include <stdint.h>

// Problem constants
#define B_   32
#define T_   2048
#define W_   1024
#define G_   16
#define D_   64
#define LIST_CAP 65536
#define BK   32

typedef __bf16 bf16_t;
typedef __bf16 bf16x8 __attribute__((ext_vector_type(8)));
typedef float  f32x4  __attribute__((ext_vector_type(4)));

// ---------------- workspace layout (bytes) ----------------
#define WS_XT      0ull
#define WS_XT_SZ   (134217728ull)                 // 32*1024*2048*2
#define WS_SUM     (WS_XT + WS_XT_SZ)             // float[32*1024]
#define WS_SQ      (WS_SUM + 131072ull)
#define WS_MU      (WS_SQ  + 131072ull)
#define WS_SIG     (WS_MU  + 131072ull)
#define WS_ACCUM   (WS_SIG + 131072ull)           // float[16] group |corr| sums
#define WS_LISTCNT (WS_ACCUM + 256ull)            // int
#define WS_LIST    (WS_LISTCNT + 256ull)          // int4[LIST_CAP]
#define WS_MASK    (WS_LIST + 1048576ull)         // uint[1024*1024] bit b = masked
#define WS_DIAG    (WS_MASK + 4194304ull)         // float[32*1024]

// ---------------- kernel 1: per-(b,w) stats + bf16 transpose ----------------
// grid (32 t-tiles, 16 w-tiles, 32 b), block 256. float4 in, bf16x8 out.
__global__ __launch_bounds__(256) void stats_transpose(
    const float* __restrict__ x, bf16_t* __restrict__ xT,
    float* __restrict__ sumb, float* __restrict__ sqb) {
  int b = blockIdx.z, t0 = blockIdx.x * 64, w0 = blockIdx.y * 64;
  __shared__ float tile[64][65];        // [w][t], padded
  __shared__ float rs[64][17], rq[64][17];
  int tid = threadIdx.x;
  int wc = tid & 15, tr = tid >> 4;     // wc: float4 col (4 w's), tr: t row 0..15
  float4 s4 = {0.f, 0.f, 0.f, 0.f}, q4 = {0.f, 0.f, 0.f, 0.f};
  const float4* xp = (const float4*)(x + ((size_t)b * T_ + t0) * W_ + w0);
#pragma unroll
  for (int p = 0; p < 4; ++p) {
    int t = tr + 16 * p;
    float4 v = xp[(size_t)t * 256 + wc];   // 256 = W_/4 row stride in float4
    s4.x += v.x; s4.y += v.y; s4.z += v.z; s4.w += v.w;
    q4.x += v.x * v.x; q4.y += v.y * v.y; q4.z += v.z * v.z; q4.w += v.w * v.w;
    tile[4 * wc + 0][t] = v.x;
    tile[4 * wc + 1][t] = v.y;
    tile[4 * wc + 2][t] = v.z;
    tile[4 * wc + 3][t] = v.w;
  }
  rs[4 * wc + 0][tr] = s4.x; rs[4 * wc + 1][tr] = s4.y;
  rs[4 * wc + 2][tr] = s4.z; rs[4 * wc + 3][tr] = s4.w;
  rq[4 * wc + 0][tr] = q4.x; rq[4 * wc + 1][tr] = q4.y;
  rq[4 * wc + 2][tr] = q4.z; rq[4 * wc + 3][tr] = q4.w;
  __syncthreads();
  if (tid < 64) {
    float s = 0.f, q = 0.f;
#pragma unroll
    for (int i = 0; i < 16; ++i) { s += rs[tid][i]; q += rq[tid][i]; }
    atomicAdd(&sumb[b * W_ + w0 + tid], s);
    atomicAdd(&sqb[b * W_ + w0 + tid], q);
  }
  // write phase: 64 w-rows x 8 chunks of 8 bf16 (16B stores)
  int c = tid & 7, wv = tid >> 3;       // c: chunk in row, wv: w row (2 passes)
#pragma unroll
  for (int p = 0; p < 2; ++p) {
    int w = wv + 32 * p;
    const float* src = &tile[w][c * 8];
    bf16x8 o;
#pragma unroll
    for (int k = 0; k < 8; ++k) o[k] = (bf16_t)src[k];
    *(bf16x8*)(xT + ((size_t)b * W_ + w0 + w) * T_ + t0 + c * 8) = o;
  }
}

__global__ void finalize_stats(const float* __restrict__ sumb,
                               const float* __restrict__ sqb,
                               float* __restrict__ mu, float* __restrict__ sig) {
  int idx = blockIdx.x * 256 + threadIdx.x;   // 32768 total
  float s = sumb[idx], q = sqb[idx];
  float m = s * (1.0f / 2048.0f);
  float var = (q - s * m) * (1.0f / 2047.0f);
  if (var < 0.f) var = 0.f;
  mu[idx] = m;
  sig[idx] = sqrtf(var);
}

// ---------------- kernel 2: batched Gram + corr epilogue ----------------
// WAVE-INDEPENDENT, ALL-REGISTER version. W=1024 = 16 panels of 64 = the G
// groups. Each WAVE owns one 64x64 panel-pair tile (pi<=pj) of one batch.
// MFMA A/B fragments are loaded DIRECTLY from global (L2-resident, XCD-pinned
// 4MB xT slice) into registers: no LDS, no barriers, no inline asm -- no hang
// classes. Explicit depth-2 pipeline (two named frag sets, static indexing);
// compiler auto-inserts counted vmcnt before each MFMA group (T4 pattern).
// grid 1088 = 8 xcd * 4 sub * 34 blocks; 136 wave-tasks (16*17/2) per batch.
__global__ __launch_bounds__(256) void gram_kernel(
    const bf16_t* __restrict__ xT, const float* __restrict__ mu,
    const float* __restrict__ sig, unsigned int* __restrict__ mask,
    float* __restrict__ diagv, int* __restrict__ listcnt,
    int4* __restrict__ list, float* __restrict__ accum) {
  int id = blockIdx.x;
  int xcd = id & 7;
  int rest = id >> 3;           // 0..135
  int sub = rest / 34;          // 0..3
  int r34 = rest % 34;          // 0..33
  int b = sub * 8 + xcd;        // XCD-pinned batch

  int tid = threadIdx.x;
  int lane = tid & 63, wave = tid >> 6;
  int task = r34 * 4 + wave;    // 0..135 upper-tri (pi,pj) of 16 panels
  int rr_ = task, pi = 0;
  while (rr_ >= 16 - pi) { rr_ -= 16 - pi; ++pi; }
  int pj = pi + rr_;
  int i0 = pi * 64, j0 = pj * 64;

  int frow = lane & 15;                    // fragment row-in-16
  int q = lane >> 4;                       // 8-element k-slot 0..3

  // lane-private fragment base addresses (16B aligned)
  const bf16_t* Abase = xT + ((size_t)b * W_ + i0 + frow) * T_ + q * 8;
  const bf16_t* Bbase = xT + ((size_t)b * W_ + j0 + frow) * T_ + q * 8;

  f32x4 zero = {0.f, 0.f, 0.f, 0.f};
  f32x4 acc[4][4];
#pragma unroll
  for (int mi = 0; mi < 4; ++mi)
#pragma unroll
    for (int nj = 0; nj < 4; ++nj) acc[mi][nj] = zero;

  bf16x8 a0[4], b0[4], a1[4], b1[4];

  auto loadAB = [&](bf16x8* Af, bf16x8* Bf, int kt) {
#pragma unroll
    for (int mi = 0; mi < 4; ++mi) {
      Af[mi] = *(const bf16x8*)(Abase + (size_t)mi * 16 * T_ + kt * BK);
      Bf[mi] = *(const bf16x8*)(Bbase + (size_t)mi * 16 * T_ + kt * BK);
    }
  };
  auto mfmaAB = [&](const bf16x8* Aq, const bf16x8* Bq) {
#pragma unroll
    for (int mi = 0; mi < 4; ++mi)
#pragma unroll
      for (int nj = 0; nj < 4; ++nj)
        acc[mi][nj] = __builtin_amdgcn_mfma_f32_16x16x32_bf16(Aq[mi], Bq[nj], acc[mi][nj], 0, 0, 0);
  };

  const int NT = T_ / BK;                  // 64
  loadAB(a0, b0, 0);                       // prologue: depth-2 pipeline
  loadAB(a1, b1, 1);
#pragma unroll 1
  for (int kt = 0; kt < NT - 2; kt += 2) {
    mfmaAB(a0, b0);                        // compiler: vmcnt waits for a0/b0
    loadAB(a0, b0, kt + 2);                // refill set 0 (8 loads in flight)
    mfmaAB(a1, b1);
    loadAB(a1, b1, kt + 3);
  }
  mfmaAB(a0, b0);                          // epilogue of pipeline
  mfmaAB(a1, b1);

  // ---- epilogue: S -> corr -> {group |corr| accum, EMA mask/list} ----
  // Diagonal tiles (pi==pj) are exactly the within-group 64x64 blocks.
  const float inv = 1.0f / 2047.0f;
  const float* mub = mu + b * W_;
  const float* sgb = sig + b * W_;
  bool diagpanel = (pi == pj);
  float gsum = 0.f;

#pragma unroll
  for (int nj = 0; nj < 4; ++nj) {
    int j = j0 + nj * 16 + frow;
    float muj = mub[j], sgj = sgb[j];
#pragma unroll
    for (int mi = 0; mi < 4; ++mi) {
#pragma unroll
      for (int rr = 0; rr < 4; ++rr) {
        int i = i0 + mi * 16 + q * 4 + rr;
        float cov = (acc[mi][nj][rr] - 2048.0f * mub[i] * muj) * inv;
        float corr = cov / (sgb[i] * sgj + 1e-8f);
        corr = fminf(1.0f, fmaxf(-1.0f, corr));
        if (diagpanel && (i != j)) gsum += fabsf(corr);
        if (fabsf(corr) > 0.5f) {
          atomicOr(&mask[i * W_ + j], 1u << b);
          if (i == j) {
            diagv[b * W_ + i] = corr;
          } else {
            int p = atomicAdd(listcnt, 1);
            if (p < LIST_CAP) list[p] = make_int4(b, i, j, __float_as_int(corr));
          }
          if (pi != pj) {
            atomicOr(&mask[j * W_ + i], 1u << b);
            int p = atomicAdd(listcnt, 1);
            if (p < LIST_CAP) list[p] = make_int4(b, j, i, __float_as_int(corr));
          }
        }
      }
    }
  }
  if (diagpanel) {
    for (int o = 32; o > 0; o >>= 1) gsum += __shfl_down(gsum, o);
    if (lane == 0) atomicAdd(&accum[pi], gsum);
  }
}

// ---------------- kernel 3: EMA scan apply ----------------
__global__ void ema_kernel(const float* __restrict__ ema,
                           const unsigned int* __restrict__ mask,
                           const float* __restrict__ diagv,
                           const int* __restrict__ listcnt,
                           const int4* __restrict__ list,
                           float* __restrict__ emaout) {
  int idx = blockIdx.x * 256 + threadIdx.x;   // 1M
  int i = idx >> 10, j = idx & 1023;
  float e = ema[idx];
  unsigned int m = mask[idx];
  if (m) {
    if (i == j) {
      for (int b = 0; b < 32; ++b)
        if ((m >> b) & 1u) e = 0.9f * e + 0.1f * diagv[b * W_ + i];
    } else {
      int cnt = *listcnt; if (cnt > LIST_CAP) cnt = LIST_CAP;
      for (int b = 0; b < 32; ++b) {
        if ((m >> b) & 1u) {
          for (int k = 0; k < cnt; ++k) {
            int4 t = list[k];
            if (t.x == b && t.y == i && t.z == j) {
              e = 0.9f * e + 0.1f * __int_as_float(t.w);
              break;
            }
          }
        }
      }
    }
  }
  emaout[idx] = e;
}

__global__ void corr_finalize(const float* __restrict__ accum, float* __restrict__ outc) {
  int g = threadIdx.x;
  if (g < 16) outc[g] = accum[g] * (1.0f / (32.0f * 4032.0f));
}

// ---------------- kernel 4: per-group expert MLP ----------------
// grid (8 t-tiles of 256, 32 b, 4 gs); block 256. Thread handles 4 t's at
// stride 64 (t = t0 + 64*tt + tl) -> per-instruction x pattern identical to
// the proven 1-t mapping, but each weight ds_read_b128 is reused across 4 t
// (weight LDS instrs / t drop 4x). Weights relaid [gl][j][d], row stride 68,
// group stride 1092: start banks {0,4,8,12}, conflict-free broadcast.
__global__ __launch_bounds__(256) void mlp_kernel(
    const float* __restrict__ x, const float* __restrict__ W1,
    const float* __restrict__ b1, const float* __restrict__ W2,
    const float* __restrict__ b2, float* __restrict__ out) {
  int b = blockIdx.y, t0 = blockIdx.x * 256, gs = blockIdx.z * 4;
  int tid = threadIdx.x;
  int gl = tid & 3, tl = tid >> 2;
  __shared__ __attribute__((aligned(16))) float Wt[4 * 1092 + 16];
  __shared__ float b1s[16 * 4], W2s[16 * 4], b2s[4];
  for (int l = tid; l < 4096; l += 256) {
    int g2 = l >> 10, r = l & 1023;       // r = j*64 + d
    int j = r >> 6, d = r & 63;
    Wt[g2 * 1092 + j * 68 + d] = W1[(size_t)(gs + g2) * 1024 + r];
  }
  if (tid < 64) {
    int g2 = tid & 3, j = tid >> 2;
    b1s[j * 4 + g2] = b1[(gs + g2) * 16 + j];
    W2s[j * 4 + g2] = W2[(gs + g2) * 16 + j];
  }
  if (tid < 4) b2s[tid] = b2[gs + tid];
  __syncthreads();

  int g = gs + gl;
  const float* xb = x + ((size_t)b * T_ + t0 + tl) * W_ + g * D_;
  const float* wbase = &Wt[gl * 1092];
  float h0[16], h1[16], h2[16], h3[16];
#pragma unroll
  for (int j = 0; j < 16; ++j) {
    float bj = b1s[j * 4 + gl];
    h0[j] = bj; h1[j] = bj; h2[j] = bj; h3[j] = bj;
  }
#pragma unroll
  for (int d4 = 0; d4 < 16; ++d4) {
    float4 x0 = *(const float4*)(xb + 0 * 64 * W_ + d4 * 4);
    float4 x1 = *(const float4*)(xb + 1 * 64 * W_ + d4 * 4);
    float4 x2 = *(const float4*)(xb + 2 * 64 * W_ + d4 * 4);
    float4 x3 = *(const float4*)(xb + 3 * 64 * W_ + d4 * 4);
#pragma unroll
    for (int j = 0; j < 16; ++j) {
      float4 wv = *(const float4*)(wbase + j * 68 + d4 * 4);
      h0[j] += x0.x * wv.x + x0.y * wv.y + x0.z * wv.z + x0.w * wv.w;
      h1[j] += x1.x * wv.x + x1.y * wv.y + x1.z * wv.z + x1.w * wv.w;
      h2[j] += x2.x * wv.x + x2.y * wv.y + x2.z * wv.z + x2.w * wv.w;
      h3[j] += x3.x * wv.x + x3.y * wv.y + x3.z * wv.z + x3.w * wv.w;
    }
  }
  size_t ob = ((size_t)b * T_ + t0 + tl) * 16 + g;
  float o0 = b2s[gl], o1 = b2s[gl], o2 = b2s[gl], o3 = b2s[gl];
#pragma unroll
  for (int j = 0; j < 16; ++j) {
    float w2 = W2s[j * 4 + gl];
    o0 += fmaxf(h0[j], 0.f) * w2;
    o1 += fmaxf(h1[j], 0.f) * w2;
    o2 += fmaxf(h2[j], 0.f) * w2;
    o3 += fmaxf(h3[j], 0.f) * w2;
  }
  out[ob + 0 * 64 * 16] = o0;
  out[ob + 1 * 64 * 16] = o1;
  out[ob + 2 * 64 * 16] = o2;
  out[ob + 3 * 64 * 16] = o3;
}

// ---------------- launch ----------------
extern "C" void kernel_launch(void* const* d_in, const int* in_sizes, int n_in,
                              void* d_out, int out_size, void* d_ws, size_t ws_size,
                              hipStream_t stream) {
  const float* x   = (const float*)d_in[0];
  const float* ema = (const float*)d_in[1];
  const float* W1  = (const float*)d_in[2];
  const float* b1  = (const float*)d_in[3];
  const float* W2  = (const float*)d_in[4];
  const float* b2  = (const float*)d_in[5];

  float* out    = (float*)d_out;          // [32][2048][16]
  float* outc   = out + 1048576;          // [16]
  float* outema = outc + 16;              // [1024][1024]

  char* ws = (char*)d_ws;
  bf16_t* xT        = (bf16_t*)(ws + WS_XT);
  float* sumb       = (float*)(ws + WS_SUM);
  float* sqb        = (float*)(ws + WS_SQ);
  float* mub        = (float*)(ws + WS_MU);
  float* sigb       = (float*)(ws + WS_SIG);
  float* accum      = (float*)(ws + WS_ACCUM);
  int*   listcnt    = (int*)(ws + WS_LISTCNT);
  int4*  list       = (int4*)(ws + WS_LIST);
  unsigned int* msk = (unsigned int*)(ws + WS_MASK);
  float* diagv      = (float*)(ws + WS_DIAG);

  hipMemsetAsync(ws + WS_SUM, 0, 262144, stream);       // sum + sq
  hipMemsetAsync(ws + WS_ACCUM, 0, 512, stream);        // accum + listcnt
  hipMemsetAsync(ws + WS_MASK, 0, 4194304, stream);     // mask bitmap

  stats_transpose<<<dim3(32, 16, 32), 256, 0, stream>>>(x, xT, sumb, sqb);
  finalize_stats<<<128, 256, 0, stream>>>(sumb, sqb, mub, sigb);
  gram_kernel<<<1088, 256, 0, stream>>>(xT, mub, sigb, msk, diagv, listcnt, list, accum);
  ema_kernel<<<4096, 256, 0, stream>>>(ema, msk, diagv, listcnt, list, outema);
  corr_finalize<<<1, 16, 0, stream>>>(accum, outc);
  mlp_kernel<<<dim3(8, 32, 4), 256, 0, stream>>>(x, W1, b1, W2, b2, out);
}

// Round 8
// 692.653 us; speedup vs baseline: 1.1739x; 1.1739x over previous
//
#include <hip/hip_runtime.h>
#include <hip/hip_bf16.h>
#include <stdint.h>

// Problem constants
#define B_   32
#define T_   2048
#define W_   1024
#define G_   16
#define D_   64
#define LIST_CAP 65536
#define BK   64

typedef __bf16 bf16_t;
typedef __bf16 bf16x8 __attribute__((ext_vector_type(8)));
typedef float  f32x4  __attribute__((ext_vector_type(4)));

// ---------------- workspace layout (bytes) ----------------
#define WS_XT      0ull
#define WS_XT_SZ   (134217728ull)                 // 32*1024*2048*2
#define WS_SUM     (WS_XT + WS_XT_SZ)             // float[32*1024]
#define WS_SQ      (WS_SUM + 131072ull)
#define WS_MU      (WS_SQ  + 131072ull)
#define WS_SIG     (WS_MU  + 131072ull)
#define WS_ACCUM   (WS_SIG + 131072ull)           // float[16] group |corr| sums
#define WS_LISTCNT (WS_ACCUM + 256ull)            // int
#define WS_LIST    (WS_LISTCNT + 256ull)          // int4[LIST_CAP]
#define WS_MASK    (WS_LIST + 1048576ull)         // uint[1024*1024] bit b = masked
#define WS_DIAG    (WS_MASK + 4194304ull)         // float[32*1024]

// ---------------- kernel 1: per-(b,w) stats + bf16 transpose ----------------
// grid (32 t-tiles, 16 w-tiles, 32 b), block 256. float4 in, bf16x8 out.
__global__ __launch_bounds__(256) void stats_transpose(
    const float* __restrict__ x, bf16_t* __restrict__ xT,
    float* __restrict__ sumb, float* __restrict__ sqb) {
  int b = blockIdx.z, t0 = blockIdx.x * 64, w0 = blockIdx.y * 64;
  __shared__ float tile[64][65];        // [w][t], padded
  __shared__ float rs[64][17], rq[64][17];
  int tid = threadIdx.x;
  int wc = tid & 15, tr = tid >> 4;     // wc: float4 col (4 w's), tr: t row 0..15
  float4 s4 = {0.f, 0.f, 0.f, 0.f}, q4 = {0.f, 0.f, 0.f, 0.f};
  const float4* xp = (const float4*)(x + ((size_t)b * T_ + t0) * W_ + w0);
#pragma unroll
  for (int p = 0; p < 4; ++p) {
    int t = tr + 16 * p;
    float4 v = xp[(size_t)t * 256 + wc];   // 256 = W_/4 row stride in float4
    s4.x += v.x; s4.y += v.y; s4.z += v.z; s4.w += v.w;
    q4.x += v.x * v.x; q4.y += v.y * v.y; q4.z += v.z * v.z; q4.w += v.w * v.w;
    tile[4 * wc + 0][t] = v.x;
    tile[4 * wc + 1][t] = v.y;
    tile[4 * wc + 2][t] = v.z;
    tile[4 * wc + 3][t] = v.w;
  }
  rs[4 * wc + 0][tr] = s4.x; rs[4 * wc + 1][tr] = s4.y;
  rs[4 * wc + 2][tr] = s4.z; rs[4 * wc + 3][tr] = s4.w;
  rq[4 * wc + 0][tr] = q4.x; rq[4 * wc + 1][tr] = q4.y;
  rq[4 * wc + 2][tr] = q4.z; rq[4 * wc + 3][tr] = q4.w;
  __syncthreads();
  if (tid < 64) {
    float s = 0.f, q = 0.f;
#pragma unroll
    for (int i = 0; i < 16; ++i) { s += rs[tid][i]; q += rq[tid][i]; }
    atomicAdd(&sumb[b * W_ + w0 + tid], s);
    atomicAdd(&sqb[b * W_ + w0 + tid], q);
  }
  // write phase: 64 w-rows x 8 chunks of 8 bf16 (16B stores)
  int c = tid & 7, wv = tid >> 3;       // c: chunk in row, wv: w row (2 passes)
#pragma unroll
  for (int p = 0; p < 2; ++p) {
    int w = wv + 32 * p;
    const float* src = &tile[w][c * 8];
    bf16x8 o;
#pragma unroll
    for (int k = 0; k < 8; ++k) o[k] = (bf16_t)src[k];
    *(bf16x8*)(xT + ((size_t)b * W_ + w0 + w) * T_ + t0 + c * 8) = o;
  }
}

__global__ void finalize_stats(const float* __restrict__ sumb,
                               const float* __restrict__ sqb,
                               float* __restrict__ mu, float* __restrict__ sig) {
  int idx = blockIdx.x * 256 + threadIdx.x;   // 32768 total
  float s = sumb[idx], q = sqb[idx];
  float m = s * (1.0f / 2048.0f);
  float var = (q - s * m) * (1.0f / 2047.0f);
  if (var < 0.f) var = 0.f;
  mu[idx] = m;
  sig[idx] = sqrtf(var);
}

// ---------------- kernel 2: batched Gram + corr epilogue ----------------
// 256x256-tile, 8-wave (512 thr) version. FULL Gram tiling: 16 tiles/batch x
// 32 batches = 512 blocks = exactly 2 clean rounds on 256 CUs (no tri tail).
// Per wave: 128x64 output (8x4 16^2 frags) -> 64 MFMA per BK=64 step, 2x the
// MFMA-per-sync of the 128^2 structure and half the LDS bytes/FLOP.
// Sync skeleton is byte-identical to the verified r2 kernel: stage(next) ->
// counted vmcnt(8) -> barrier -> ds_read+MFMA -> lgkmcnt(0)+sched_barrier ->
// barrier. All barriers uniform control flow (no hang class).
// LDS 128 KB (2 dbuf x (A 256x64 + B 256x64) bf16) -> 1 block/CU.
__global__ __launch_bounds__(512) void gram_kernel(
    const bf16_t* __restrict__ xT, const float* __restrict__ mu,
    const float* __restrict__ sig, unsigned int* __restrict__ mask,
    float* __restrict__ diagv, int* __restrict__ listcnt,
    int4* __restrict__ list, float* __restrict__ accum) {
  int id = blockIdx.x;            // 0..511
  int xcd = id & 7;
  int loc = id >> 3;              // 0..63
  int sub = loc >> 4;             // 0..3  (batch-major after xcd: L2 locality)
  int tl  = loc & 15;             // 0..15 tile within batch
  int ti = tl >> 2, tj = tl & 3;  // 4x4 tile grid of 256
  int b = sub * 8 + xcd;          // XCD-pinned batch
  int i0 = ti * 256, j0 = tj * 256;

  const bf16_t* Ag = xT + ((size_t)b * W_ + i0) * T_;
  const bf16_t* Bg = xT + ((size_t)b * W_ + j0) * T_;

  __shared__ __attribute__((aligned(16))) bf16_t As[2][256 * BK];  // 2 x 32 KB
  __shared__ __attribute__((aligned(16))) bf16_t Bs[2][256 * BK];  // 2 x 32 KB

  int tid = threadIdx.x;
  int lane = tid & 63, wave = tid >> 6;    // 8 waves
  int wm = wave >> 2, wn = wave & 3;       // 2 x 4 wave grid -> 128x64 each

  // stage one BK=64 slice of A and B (256 rows each): 2048 16B chunks per
  // matrix, 512 threads -> 4 chunks each -> 8 global_load_lds / thread.
  // Chunk-XOR swizzle identical to the verified r2 kernel (128B rows, 8 slots):
  // LDS dest linear, global source permuted; inverted on the ds_read side.
  auto stage = [&](int buf, int k0) {
    bf16_t* Ad = &As[buf][0];
    bf16_t* Bd = &Bs[buf][0];
#pragma unroll
    for (int s = 0; s < 4; ++s) {
      int c = s * 512 + tid;               // 0..2047 linear 16B chunk
      int row = c >> 3, slot = c & 7;
      int gslot = slot ^ (row & 7);        // XOR swizzle (source permute)
      __builtin_amdgcn_global_load_lds(
          (const __attribute__((address_space(1))) void*)(Ag + (size_t)row * T_ + k0 + gslot * 8),
          (__attribute__((address_space(3))) void*)(Ad + c * 8), 16, 0, 0);
      __builtin_amdgcn_global_load_lds(
          (const __attribute__((address_space(1))) void*)(Bg + (size_t)row * T_ + k0 + gslot * 8),
          (__attribute__((address_space(3))) void*)(Bd + c * 8), 16, 0, 0);
    }
  };

  f32x4 zero = {0.f, 0.f, 0.f, 0.f};
  f32x4 acc[8][4];
#pragma unroll
  for (int mi = 0; mi < 8; ++mi)
#pragma unroll
    for (int nj = 0; nj < 4; ++nj) acc[mi][nj] = zero;

  // fragment base rows within the 256-tile
  int arow = wm * 128 + (lane & 15);
  int brow = wn * 64 + (lane & 15);
  int q = lane >> 4;                       // k-quarter within 32-slice

  stage(0, 0);                             // prologue: 8 loads in flight

  const int NT = T_ / BK;                  // 32
#pragma unroll 1
  for (int kt = 0; kt < NT; ++kt) {
    int cur = kt & 1;
    if (kt + 1 < NT) {
      stage(cur ^ 1, (kt + 1) * BK);       // +8 loads (<=16 outstanding)
      asm volatile("s_waitcnt vmcnt(8)" ::: "memory");   // tile kt's 8 done
    } else {
      asm volatile("s_waitcnt vmcnt(0)" ::: "memory");
    }
    __builtin_amdgcn_s_barrier();          // all waves: buf[cur] fully staged
    __builtin_amdgcn_sched_barrier(0);

    const bf16_t* Ac = &As[cur][0];
    const bf16_t* Bc = &Bs[cur][0];
#pragma unroll
    for (int s2 = 0; s2 < 2; ++s2) {       // two 32-k MFMA steps per stage
      bf16x8 af[8], bfr[4];
#pragma unroll
      for (int mi = 0; mi < 8; ++mi) {
        int row = arow + mi * 16;
        af[mi] = *(const bf16x8*)(Ac + row * BK + ((s2 * 4 + q) ^ (row & 7)) * 8);
      }
#pragma unroll
      for (int nj = 0; nj < 4; ++nj) {
        int row = brow + nj * 16;
        bfr[nj] = *(const bf16x8*)(Bc + row * BK + ((s2 * 4 + q) ^ (row & 7)) * 8);
      }
#pragma unroll
      for (int mi = 0; mi < 8; ++mi)
#pragma unroll
        for (int nj = 0; nj < 4; ++nj)
          acc[mi][nj] = __builtin_amdgcn_mfma_f32_16x16x32_bf16(af[mi], bfr[nj], acc[mi][nj], 0, 0, 0);
    }
    // ds_reads must retire before next iter's stage overwrites buf[cur]
    asm volatile("s_waitcnt lgkmcnt(0)" ::: "memory");
    __builtin_amdgcn_sched_barrier(0);
    __builtin_amdgcn_s_barrier();          // all waves done reading buf[cur]
  }

  // ---- epilogue: S -> corr -> {group |corr| accum, EMA mask/list} ----
  // Full tiling: every (i,j) computed directly -> no mirror emission.
  // Group-diag elements: (i>>6)==(j>>6); per wave the j-range spans exactly
  // one group (wn*64 is 64-aligned) -> accum index tj*4+wn is wave-uniform.
  const float inv = 1.0f / 2047.0f;
  const float* mub = mu + b * W_;
  const float* sgb = sig + b * W_;
  float gsum = 0.f;

#pragma unroll
  for (int nj = 0; nj < 4; ++nj) {
    int j = j0 + wn * 64 + nj * 16 + (lane & 15);
    float muj = mub[j], sgj = sgb[j];
#pragma unroll
    for (int mi = 0; mi < 8; ++mi) {
#pragma unroll
      for (int rr = 0; rr < 4; ++rr) {
        int i = i0 + wm * 128 + mi * 16 + q * 4 + rr;
        float cov = (acc[mi][nj][rr] - 2048.0f * mub[i] * muj) * inv;
        float corr = cov / (sgb[i] * sgj + 1e-8f);
        corr = fminf(1.0f, fmaxf(-1.0f, corr));
        if (((i >> 6) == (j >> 6)) && (i != j)) gsum += fabsf(corr);
        if (fabsf(corr) > 0.5f) {
          atomicOr(&mask[i * W_ + j], 1u << b);
          if (i == j) {
            diagv[b * W_ + i] = corr;
          } else {
            int p = atomicAdd(listcnt, 1);
            if (p < LIST_CAP) list[p] = make_int4(b, i, j, __float_as_int(corr));
          }
        }
      }
    }
  }
  // only waves whose row-range overlaps their j-group can have gsum != 0
  if ((ti == tj) && ((wn >> 1) == wm)) {
    for (int o = 32; o > 0; o >>= 1) gsum += __shfl_down(gsum, o);
    if (lane == 0) atomicAdd(&accum[tj * 4 + wn], gsum);
  }
}

// ---------------- kernel 3: EMA scan apply ----------------
__global__ void ema_kernel(const float* __restrict__ ema,
                           const unsigned int* __restrict__ mask,
                           const float* __restrict__ diagv,
                           const int* __restrict__ listcnt,
                           const int4* __restrict__ list,
                           float* __restrict__ emaout) {
  int idx = blockIdx.x * 256 + threadIdx.x;   // 1M
  int i = idx >> 10, j = idx & 1023;
  float e = ema[idx];
  unsigned int m = mask[idx];
  if (m) {
    if (i == j) {
      for (int b = 0; b < 32; ++b)
        if ((m >> b) & 1u) e = 0.9f * e + 0.1f * diagv[b * W_ + i];
    } else {
      int cnt = *listcnt; if (cnt > LIST_CAP) cnt = LIST_CAP;
      for (int b = 0; b < 32; ++b) {
        if ((m >> b) & 1u) {
          for (int k = 0; k < cnt; ++k) {
            int4 t = list[k];
            if (t.x == b && t.y == i && t.z == j) {
              e = 0.9f * e + 0.1f * __int_as_float(t.w);
              break;
            }
          }
        }
      }
    }
  }
  emaout[idx] = e;
}

__global__ void corr_finalize(const float* __restrict__ accum, float* __restrict__ outc) {
  int g = threadIdx.x;
  if (g < 16) outc[g] = accum[g] * (1.0f / (32.0f * 4032.0f));
}

// ---------------- kernel 4: per-group expert MLP ----------------
// grid (8 t-tiles of 256, 32 b, 4 gs); block 256. Thread handles 4 t's at
// stride 64 (t = t0 + 64*tt + tl) -> per-instruction x pattern identical to
// the proven 1-t mapping, but each weight ds_read_b128 is reused across 4 t
// (weight LDS instrs / t drop 4x). Weights relaid [gl][j][d], row stride 68,
// group stride 1092: start banks {0,4,8,12}, conflict-free broadcast.
__global__ __launch_bounds__(256) void mlp_kernel(
    const float* __restrict__ x, const float* __restrict__ W1,
    const float* __restrict__ b1, const float* __restrict__ W2,
    const float* __restrict__ b2, float* __restrict__ out) {
  int b = blockIdx.y, t0 = blockIdx.x * 256, gs = blockIdx.z * 4;
  int tid = threadIdx.x;
  int gl = tid & 3, tl = tid >> 2;
  __shared__ __attribute__((aligned(16))) float Wt[4 * 1092 + 16];
  __shared__ float b1s[16 * 4], W2s[16 * 4], b2s[4];
  for (int l = tid; l < 4096; l += 256) {
    int g2 = l >> 10, r = l & 1023;       // r = j*64 + d
    int j = r >> 6, d = r & 63;
    Wt[g2 * 1092 + j * 68 + d] = W1[(size_t)(gs + g2) * 1024 + r];
  }
  if (tid < 64) {
    int g2 = tid & 3, j = tid >> 2;
    b1s[j * 4 + g2] = b1[(gs + g2) * 16 + j];
    W2s[j * 4 + g2] = W2[(gs + g2) * 16 + j];
  }
  if (tid < 4) b2s[tid] = b2[gs + tid];
  __syncthreads();

  int g = gs + gl;
  const float* xb = x + ((size_t)b * T_ + t0 + tl) * W_ + g * D_;
  const float* wbase = &Wt[gl * 1092];
  float h0[16], h1[16], h2[16], h3[16];
#pragma unroll
  for (int j = 0; j < 16; ++j) {
    float bj = b1s[j * 4 + gl];
    h0[j] = bj; h1[j] = bj; h2[j] = bj; h3[j] = bj;
  }
#pragma unroll
  for (int d4 = 0; d4 < 16; ++d4) {
    float4 x0 = *(const float4*)(xb + 0 * 64 * W_ + d4 * 4);
    float4 x1 = *(const float4*)(xb + 1 * 64 * W_ + d4 * 4);
    float4 x2 = *(const float4*)(xb + 2 * 64 * W_ + d4 * 4);
    float4 x3 = *(const float4*)(xb + 3 * 64 * W_ + d4 * 4);
#pragma unroll
    for (int j = 0; j < 16; ++j) {
      float4 wv = *(const float4*)(wbase + j * 68 + d4 * 4);
      h0[j] += x0.x * wv.x + x0.y * wv.y + x0.z * wv.z + x0.w * wv.w;
      h1[j] += x1.x * wv.x + x1.y * wv.y + x1.z * wv.z + x1.w * wv.w;
      h2[j] += x2.x * wv.x + x2.y * wv.y + x2.z * wv.z + x2.w * wv.w;
      h3[j] += x3.x * wv.x + x3.y * wv.y + x3.z * wv.z + x3.w * wv.w;
    }
  }
  size_t ob = ((size_t)b * T_ + t0 + tl) * 16 + g;
  float o0 = b2s[gl], o1 = b2s[gl], o2 = b2s[gl], o3 = b2s[gl];
#pragma unroll
  for (int j = 0; j < 16; ++j) {
    float w2 = W2s[j * 4 + gl];
    o0 += fmaxf(h0[j], 0.f) * w2;
    o1 += fmaxf(h1[j], 0.f) * w2;
    o2 += fmaxf(h2[j], 0.f) * w2;
    o3 += fmaxf(h3[j], 0.f) * w2;
  }
  out[ob + 0 * 64 * 16] = o0;
  out[ob + 1 * 64 * 16] = o1;
  out[ob + 2 * 64 * 16] = o2;
  out[ob + 3 * 64 * 16] = o3;
}

// ---------------- launch ----------------
extern "C" void kernel_launch(void* const* d_in, const int* in_sizes, int n_in,
                              void* d_out, int out_size, void* d_ws, size_t ws_size,
                              hipStream_t stream) {
  const float* x   = (const float*)d_in[0];
  const float* ema = (const float*)d_in[1];
  const float* W1  = (const float*)d_in[2];
  const float* b1  = (const float*)d_in[3];
  const float* W2  = (const float*)d_in[4];
  const float* b2  = (const float*)d_in[5];

  float* out    = (float*)d_out;          // [32][2048][16]
  float* outc   = out + 1048576;          // [16]
  float* outema = outc + 16;              // [1024][1024]

  char* ws = (char*)d_ws;
  bf16_t* xT        = (bf16_t*)(ws + WS_XT);
  float* sumb       = (float*)(ws + WS_SUM);
  float* sqb        = (float*)(ws + WS_SQ);
  float* mub        = (float*)(ws + WS_MU);
  float* sigb       = (float*)(ws + WS_SIG);
  float* accum      = (float*)(ws + WS_ACCUM);
  int*   listcnt    = (int*)(ws + WS_LISTCNT);
  int4*  list       = (int4*)(ws + WS_LIST);
  unsigned int* msk = (unsigned int*)(ws + WS_MASK);
  float* diagv      = (float*)(ws + WS_DIAG);

  hipMemsetAsync(ws + WS_SUM, 0, 262144, stream);       // sum + sq
  hipMemsetAsync(ws + WS_ACCUM, 0, 512, stream);        // accum + listcnt
  hipMemsetAsync(ws + WS_MASK, 0, 4194304, stream);     // mask bitmap

  stats_transpose<<<dim3(32, 16, 32), 256, 0, stream>>>(x, xT, sumb, sqb);
  finalize_stats<<<128, 256, 0, stream>>>(sumb, sqb, mub, sigb);
  gram_kernel<<<512, 512, 0, stream>>>(xT, mub, sigb, msk, diagv, listcnt, list, accum);
  ema_kernel<<<4096, 256, 0, stream>>>(ema, msk, diagv, listcnt, list, outema);
  corr_finalize<<<1, 16, 0, stream>>>(accum, outc);
  mlp_kernel<<<dim3(8, 32, 4), 256, 0, stream>>>(x, W1, b1, W2, b2, out);
}